// Round 1
// baseline (549.845 us; speedup 1.0000x reference)
//
#include <hip/hip_runtime.h>
#include <hip/hip_bf16.h>
#include <math.h>

#define N_TOKENS 16384
#define DIM      4096
#define NEXP     128
#define TOPK     8
#define NFLAT    (N_TOKENS * TOPK)   // 131072

// ---- workspace layout (bytes) ----
#define COUNTS_OFF  0                            // 128 int
#define SEL_OFF     1024                         // 131072 int
#define WGT_OFF     (SEL_OFF + NFLAT * 4)        // 131072 float
#define PARTIAL_OFF (WGT_OFF + NFLAT * 4)        // slices*128*16384 float (multiple of 256)

// ======================= GEMM: scores = x @ gate_w^T =======================
// Block: 256 threads, tile = 128 tokens x 128 experts x (DIM/slices) K.
// Per-thread 8x8 fp32 register tile; LDS stages x and w transposed [k][row].
#define BT 128
#define KC 32

__global__ __launch_bounds__(256, 2)
void gemm_kernel(const float* __restrict__ x, const float* __restrict__ gw,
                 float* __restrict__ partial, int kper) {
    __shared__ float xs[KC][BT];    // [k][token]
    __shared__ float wsm[KC][NEXP]; // [k][expert]

    const int tid  = threadIdx.x;
    const int tx   = tid & 15;       // expert group
    const int ty   = tid >> 4;       // token group
    const int tok0 = blockIdx.x * BT;
    const int kbase = blockIdx.y * kper;
    const int t0 = ty * 8, e0 = tx * 8;

    float acc[8][8];
#pragma unroll
    for (int i = 0; i < 8; i++)
#pragma unroll
        for (int j = 0; j < 8; j++) acc[i][j] = 0.f;

    for (int kc = 0; kc < kper; kc += KC) {
        // ---- stage x tile and w tile (transposed) ----
#pragma unroll
        for (int q = 0; q < 4; q++) {
            int s   = tid + q * 256;      // 0..1023 float4 slots
            int row = s >> 3;             // 0..127
            int kq  = s & 7;              // 0..7 (float4 within KC)
            float4 vx = *(const float4*)&x[(size_t)(tok0 + row) * DIM + kbase + kc + kq * 4];
            xs[kq * 4 + 0][row] = vx.x; xs[kq * 4 + 1][row] = vx.y;
            xs[kq * 4 + 2][row] = vx.z; xs[kq * 4 + 3][row] = vx.w;
            float4 vw = *(const float4*)&gw[(size_t)row * DIM + kbase + kc + kq * 4];
            wsm[kq * 4 + 0][row] = vw.x; wsm[kq * 4 + 1][row] = vw.y;
            wsm[kq * 4 + 2][row] = vw.z; wsm[kq * 4 + 3][row] = vw.w;
        }
        __syncthreads();
        // ---- compute ----
#pragma unroll
        for (int k = 0; k < KC; k++) {
            float4 xa = *(const float4*)&xs[k][t0];
            float4 xb = *(const float4*)&xs[k][t0 + 4];
            float4 wa = *(const float4*)&wsm[k][e0];
            float4 wb = *(const float4*)&wsm[k][e0 + 4];
            float xr[8] = {xa.x, xa.y, xa.z, xa.w, xb.x, xb.y, xb.z, xb.w};
            float wr[8] = {wa.x, wa.y, wa.z, wa.w, wb.x, wb.y, wb.z, wb.w};
#pragma unroll
            for (int i = 0; i < 8; i++)
#pragma unroll
                for (int j = 0; j < 8; j++) acc[i][j] = fmaf(xr[i], wr[j], acc[i][j]);
        }
        __syncthreads();
    }

    // ---- epilogue: partial[slice][expert][token], token-contiguous float4 ----
    const int s = blockIdx.y;
#pragma unroll
    for (int j = 0; j < 8; j++) {
        float4 v0 = make_float4(acc[0][j], acc[1][j], acc[2][j], acc[3][j]);
        float4 v1 = make_float4(acc[4][j], acc[5][j], acc[6][j], acc[7][j]);
        size_t base = (size_t)(s * NEXP + e0 + j) * N_TOKENS + tok0 + t0;
        *(float4*)&partial[base]     = v0;
        *(float4*)&partial[base + 4] = v1;
    }
}

// ======================= top-8 + softmax-over-8 =======================
// Thread per token; partial reads coalesced over tokens. Strict-> insertion
// keeps ties in favor of the lower expert index (stable argsort semantics).
__global__ void topk_kernel(const float* __restrict__ partial, int slices,
                            float* __restrict__ wgt, int* __restrict__ sel,
                            int* __restrict__ counts) {
    const int t = blockIdx.x * blockDim.x + threadIdx.x;
    float bs[8];
    int   bi[8];
#pragma unroll
    for (int j = 0; j < 8; j++) { bs[j] = -3.0e38f; bi[j] = 0; }

    for (int e = 0; e < NEXP; e++) {
        float s = 0.f;
        for (int k = 0; k < slices; k++)
            s += partial[(size_t)(k * NEXP + e) * N_TOKENS + t];
        if (s > bs[7]) {
            int pos = 7;
#pragma unroll
            for (int q = 6; q >= 0; q--) pos = (s > bs[q]) ? q : pos;
#pragma unroll
            for (int q = 7; q >= 1; q--) {
                bool sh = (q > pos);
                bs[q] = sh ? bs[q - 1] : bs[q];
                bi[q] = sh ? bi[q - 1] : bi[q];
            }
#pragma unroll
            for (int q = 0; q < 8; q++)
                if (q == pos) { bs[q] = s; bi[q] = e; }
        }
    }

    // softmax over the selected 8 (global softmax Z cancels in renormalization)
    float m = bs[0], sum = 0.f, ex[8];
#pragma unroll
    for (int j = 0; j < 8; j++) { ex[j] = expf(bs[j] - m); sum += ex[j]; }
    float inv = 1.f / fmaxf(sum, 1e-8f);
#pragma unroll
    for (int j = 0; j < 8; j++) {
        wgt[t * TOPK + j] = ex[j] * inv;
        sel[t * TOPK + j] = bi[j];
    }
#pragma unroll
    for (int j = 0; j < 8; j++) atomicAdd(&counts[bi[j]], 1);
}

// ======================= stable counting-sort emit =======================
// One block per expert; scans flat sel[] in order, stable compaction via
// ballot/shuffle prefix sums. Also emits num_tokens_per_expert (as f32).
__global__ void sort_kernel(const int* __restrict__ sel, const float* __restrict__ wgt,
                            const int* __restrict__ counts, float* __restrict__ out) {
    const int e   = blockIdx.x;
    const int tid = threadIdx.x;
    __shared__ int s_cnt[NEXP];
    __shared__ int s_wtot[8];
    if (tid < NEXP) s_cnt[tid] = counts[tid];
    __syncthreads();
    int off = 0;
    for (int i = 0; i < e; i++) off += s_cnt[i];
    if (tid == 0) out[2 * NFLAT + e] = (float)s_cnt[e];

    const int lane = tid & 63, wid = tid >> 6;
    for (int base = 0; base < NFLAT; base += 2048) {  // 512 thr * 4 elems
        const int i0 = base + tid * 4;
        const int4 v = *(const int4*)&sel[i0];
        int f0 = (v.x == e), f1 = (v.y == e), f2 = (v.z == e), f3 = (v.w == e);
        int c = f0 + f1 + f2 + f3;
        int sc = c;
#pragma unroll
        for (int d = 1; d < 64; d <<= 1) {
            int o = __shfl_up(sc, d);
            sc += (lane >= d) ? o : 0;
        }
        if (lane == 63) s_wtot[wid] = sc;
        __syncthreads();
        int wbase = 0, total = 0;
#pragma unroll
        for (int w = 0; w < 8; w++) {
            wbase += (w < wid) ? s_wtot[w] : 0;
            total += s_wtot[w];
        }
        int p = off + wbase + (sc - c);  // exclusive prefix for this thread
        if (f0) { out[p] = wgt[i0];     out[NFLAT + p] = (float)((i0) >> 3);     p++; }
        if (f1) { out[p] = wgt[i0 + 1]; out[NFLAT + p] = (float)((i0 + 1) >> 3); p++; }
        if (f2) { out[p] = wgt[i0 + 2]; out[NFLAT + p] = (float)((i0 + 2) >> 3); p++; }
        if (f3) { out[p] = wgt[i0 + 3]; out[NFLAT + p] = (float)((i0 + 3) >> 3); p++; }
        off += total;
        __syncthreads();
    }
}

extern "C" void kernel_launch(void* const* d_in, const int* in_sizes, int n_in,
                              void* d_out, int out_size, void* d_ws, size_t ws_size,
                              hipStream_t stream) {
    const float* x  = (const float*)d_in[0];
    const float* gw = (const float*)d_in[1];
    float* out = (float*)d_out;
    char*  ws  = (char*)d_ws;

    int*   counts  = (int*)(ws + COUNTS_OFF);
    int*   sel     = (int*)(ws + SEL_OFF);
    float* wgt     = (float*)(ws + WGT_OFF);
    float* partial = (float*)(ws + PARTIAL_OFF);

    // split-K factor sized to workspace (4 -> 2 -> 1)
    int slices = 4;
    while (slices > 1 &&
           PARTIAL_OFF + (size_t)slices * NEXP * N_TOKENS * 4 > ws_size)
        slices >>= 1;
    int kper = DIM / slices;

    hipMemsetAsync(counts, 0, NEXP * sizeof(int), stream);

    dim3 g1(N_TOKENS / BT, slices);
    gemm_kernel<<<g1, 256, 0, stream>>>(x, gw, partial, kper);
    topk_kernel<<<N_TOKENS / 256, 256, 0, stream>>>(partial, slices, wgt, sel, counts);
    sort_kernel<<<NEXP, 512, 0, stream>>>(sel, wgt, counts, out);
}

// Round 2
// 401.337 us; speedup vs baseline: 1.3700x; 1.3700x over previous
//
#include <hip/hip_runtime.h>
#include <math.h>

#define NT    16384
#define DIM   4096
#define NEXP  128
#define TOPK  8
#define NFLAT (NT * TOPK)        // 131072
#define NBLK  (NFLAT / 256)      // 512 hist/scatter blocks

// ---- workspace layout (bytes) ----
#define COUNTS_OFF 0                               // 128 int (memset)
#define GBASE_OFF  512                             // 128 int
#define SEL_OFF    1024                            // NFLAT int
#define WGT_OFF    (SEL_OFF + NFLAT * 4)           // NFLAT float
#define BH_OFF     (WGT_OFF + NFLAT * 4)           // NEXP*NBLK int (block hists)
#define BO_OFF     (BH_OFF + NEXP * NBLK * 4)      // NEXP*NBLK int (block offsets)
#define PART_OFF   (BO_OFF + NEXP * NBLK * 4)      // slices*NEXP*NT float

// ======================= GEMM: partial[s][e][t] = x @ gate_w^T ==============
#define BT  128
#define KC  32
#define LDP 132   // pad 4: keeps 16B alignment for b128 (132*4=528=33*16),
                  // breaks the stride-128 (==0 mod 32 banks) write conflict.

__global__ __launch_bounds__(256, 4)
void gemm_kernel(const float* __restrict__ x, const float* __restrict__ gw,
                 float* __restrict__ partial, int kper) {
    __shared__ float xs[KC][LDP];   // [k][token]
    __shared__ float wsm[KC][LDP];  // [k][expert]

    const int tid = threadIdx.x;
    const int tx = tid & 15, ty = tid >> 4;
    const int tok0 = blockIdx.x * BT;
    const int kbase = blockIdx.y * kper;

    float acc[8][8];
#pragma unroll
    for (int i = 0; i < 8; i++)
#pragma unroll
        for (int j = 0; j < 8; j++) acc[i][j] = 0.f;

    for (int kc = 0; kc < kper; kc += KC) {
#pragma unroll
        for (int q = 0; q < 4; q++) {
            int s = tid + q * 256;          // 1024 float4 slots
            int row = s >> 3, kq = s & 7;
            float4 v = *(const float4*)&x[(size_t)(tok0 + row) * DIM + kbase + kc + kq * 4];
            xs[kq * 4 + 0][row] = v.x; xs[kq * 4 + 1][row] = v.y;
            xs[kq * 4 + 2][row] = v.z; xs[kq * 4 + 3][row] = v.w;
            float4 w = *(const float4*)&gw[(size_t)row * DIM + kbase + kc + kq * 4];
            wsm[kq * 4 + 0][row] = w.x; wsm[kq * 4 + 1][row] = w.y;
            wsm[kq * 4 + 2][row] = w.z; wsm[kq * 4 + 3][row] = w.w;
        }
        __syncthreads();
#pragma unroll
        for (int k = 0; k < KC; k++) {
            // split tiles: {tx*4..+3} and {64+tx*4..+3} -> 2-way banks (free)
            float4 xa = *(const float4*)&xs[k][ty * 4];
            float4 xb = *(const float4*)&xs[k][64 + ty * 4];
            float4 wa = *(const float4*)&wsm[k][tx * 4];
            float4 wb = *(const float4*)&wsm[k][64 + tx * 4];
            float xr[8] = {xa.x, xa.y, xa.z, xa.w, xb.x, xb.y, xb.z, xb.w};
            float wr[8] = {wa.x, wa.y, wa.z, wa.w, wb.x, wb.y, wb.z, wb.w};
#pragma unroll
            for (int i = 0; i < 8; i++)
#pragma unroll
                for (int j = 0; j < 8; j++) acc[i][j] = fmaf(xr[i], wr[j], acc[i][j]);
        }
        __syncthreads();
    }

    const int s = blockIdx.y;
#pragma unroll
    for (int j = 0; j < 8; j++) {
        int e = (j < 4) ? tx * 4 + j : 64 + tx * 4 + (j - 4);
        size_t base = (size_t)(s * NEXP + e) * NT + tok0;
        *(float4*)&partial[base + ty * 4] =
            make_float4(acc[0][j], acc[1][j], acc[2][j], acc[3][j]);
        *(float4*)&partial[base + 64 + ty * 4] =
            make_float4(acc[4][j], acc[5][j], acc[6][j], acc[7][j]);
    }
}

// ======================= top-8 + softmax-over-8 =======================
template <int S>
__global__ void topk_kernel(const float* __restrict__ partial,
                            float* __restrict__ wgt, int* __restrict__ sel,
                            int* __restrict__ counts) {
    const int t = blockIdx.x * blockDim.x + threadIdx.x;
    float bs[8];
    int bi[8];
#pragma unroll
    for (int j = 0; j < 8; j++) { bs[j] = -3.0e38f; bi[j] = 0; }

#pragma unroll 4
    for (int e = 0; e < NEXP; e++) {
        float s = 0.f;
#pragma unroll
        for (int k = 0; k < S; k++)
            s += partial[(size_t)(k * NEXP + e) * NT + t];
        if (s > bs[7]) {
            int pos = 7;
#pragma unroll
            for (int q = 6; q >= 0; q--) pos = (s > bs[q]) ? q : pos;
#pragma unroll
            for (int q = 7; q >= 1; q--) {
                bool sh = (q > pos);
                bs[q] = sh ? bs[q - 1] : bs[q];
                bi[q] = sh ? bi[q - 1] : bi[q];
            }
#pragma unroll
            for (int q = 0; q < 8; q++)
                if (q == pos) { bs[q] = s; bi[q] = e; }
        }
    }

    float m = bs[0], sum = 0.f, ex[8];
#pragma unroll
    for (int j = 0; j < 8; j++) { ex[j] = expf(bs[j] - m); sum += ex[j]; }
    float inv = 1.f / fmaxf(sum, 1e-8f);
#pragma unroll
    for (int j = 0; j < 8; j++) {
        wgt[t * TOPK + j] = ex[j] * inv;
        sel[t * TOPK + j] = bi[j];
    }
#pragma unroll
    for (int j = 0; j < 8; j++) atomicAdd(&counts[bi[j]], 1);
}

// ======================= stable sort: 3-pass rank =======================
// Pass 1: per-256-entry-block expert histogram.
__global__ void hist_kernel(const int* __restrict__ sel, int* __restrict__ bh) {
    __shared__ int h[NEXP];
    const int tid = threadIdx.x, b = blockIdx.x;
    if (tid < NEXP) h[tid] = 0;
    __syncthreads();
    atomicAdd(&h[sel[b * 256 + tid]], 1);
    __syncthreads();
    if (tid < NEXP) bh[tid * NBLK + b] = h[tid];   // [e][b]
}

// Pass 2: per-expert exclusive scan over the 512 blocks; also expert bases
// and the num_tokens_per_expert output.
__global__ void scan_kernel(const int* __restrict__ bh, int* __restrict__ bo,
                            const int* __restrict__ counts, int* __restrict__ gbase,
                            float* __restrict__ out) {
    const int e = blockIdx.x, tid = threadIdx.x;     // 512 threads
    const int lane = tid & 63, wid = tid >> 6;
    int v = bh[e * NBLK + tid];
    int sc = v;
#pragma unroll
    for (int d = 1; d < 64; d <<= 1) {
        int o = __shfl_up(sc, d);
        sc += (lane >= d) ? o : 0;
    }
    __shared__ int wsum[8];
    if (lane == 63) wsum[wid] = sc;
    __syncthreads();
    int add = 0;
#pragma unroll
    for (int w = 0; w < 8; w++) add += (w < wid) ? wsum[w] : 0;
    bo[e * NBLK + tid] = sc - v + add;               // exclusive
    if (tid == 0) {
        int g = 0;
        for (int i = 0; i < e; i++) g += counts[i];
        gbase[e] = g;
        out[2 * NFLAT + e] = (float)counts[e];
    }
}

// Pass 3: scatter with stable in-block rank (match-any via 7 ballots).
__global__ void scatter_kernel(const int* __restrict__ sel, const float* __restrict__ wgt,
                               const int* __restrict__ bo, const int* __restrict__ gbase,
                               float* __restrict__ out) {
    const int tid = threadIdx.x, b = blockIdx.x;
    const int i = b * 256 + tid;
    const int e = sel[i];
    const int lane = tid & 63, wid = tid >> 6;
    unsigned long long m = ~0ull;
#pragma unroll
    for (int bit = 0; bit < 7; bit++) {
        unsigned long long bal = __ballot((e >> bit) & 1);
        m &= ((e >> bit) & 1) ? bal : ~bal;
    }
    unsigned long long lower = (lane == 0) ? 0ull : (~0ull >> (64 - lane));
    int wrank = __popcll(m & lower);

    __shared__ int wh[4][NEXP];
    ((int*)wh)[tid] = 0; ((int*)wh)[tid + 256] = 0;
    __syncthreads();
    if (wrank == 0) wh[wid][e] = __popcll(m);
    __syncthreads();
    int off = 0;
#pragma unroll
    for (int w = 0; w < 4; w++) off += (w < wid) ? wh[w][e] : 0;

    int pos = gbase[e] + bo[e * NBLK + b] + off + wrank;
    out[pos] = wgt[i];
    out[NFLAT + pos] = (float)(i >> 3);
}

extern "C" void kernel_launch(void* const* d_in, const int* in_sizes, int n_in,
                              void* d_out, int out_size, void* d_ws, size_t ws_size,
                              hipStream_t stream) {
    const float* x  = (const float*)d_in[0];
    const float* gw = (const float*)d_in[1];
    float* out = (float*)d_out;
    char*  ws  = (char*)d_ws;

    int*   counts  = (int*)(ws + COUNTS_OFF);
    int*   gbase   = (int*)(ws + GBASE_OFF);
    int*   sel     = (int*)(ws + SEL_OFF);
    float* wgt     = (float*)(ws + WGT_OFF);
    int*   bh      = (int*)(ws + BH_OFF);
    int*   bo      = (int*)(ws + BO_OFF);
    float* partial = (float*)(ws + PART_OFF);

    int slices = 8;
    while (slices > 1 &&
           (size_t)PART_OFF + (size_t)slices * NEXP * NT * 4 > ws_size)
        slices >>= 1;
    int kper = DIM / slices;

    hipMemsetAsync(counts, 0, NEXP * sizeof(int), stream);

    dim3 g1(NT / BT, slices);
    gemm_kernel<<<g1, 256, 0, stream>>>(x, gw, partial, kper);

    switch (slices) {
        case 8: topk_kernel<8><<<NT / 256, 256, 0, stream>>>(partial, wgt, sel, counts); break;
        case 4: topk_kernel<4><<<NT / 256, 256, 0, stream>>>(partial, wgt, sel, counts); break;
        case 2: topk_kernel<2><<<NT / 256, 256, 0, stream>>>(partial, wgt, sel, counts); break;
        default: topk_kernel<1><<<NT / 256, 256, 0, stream>>>(partial, wgt, sel, counts); break;
    }

    hist_kernel<<<NBLK, 256, 0, stream>>>(sel, bh);
    scan_kernel<<<NEXP, 512, 0, stream>>>(bh, bo, counts, gbase, out);
    scatter_kernel<<<NBLK, 256, 0, stream>>>(sel, wgt, bo, gbase, out);
}

// Round 3
// 381.777 us; speedup vs baseline: 1.4402x; 1.0512x over previous
//
#include <hip/hip_runtime.h>
#include <math.h>

typedef _Float16 f16;
typedef f16 f16x8 __attribute__((ext_vector_type(8)));
typedef float f32x4 __attribute__((ext_vector_type(4)));

#define NT    16384
#define DIM   4096
#define NEXP  128
#define TOPK  8
#define NFLAT (NT * TOPK)        // 131072
#define NBLK  (NFLAT / 256)      // 512
#define KSPLIT 4
#define KPER  (DIM / KSPLIT)     // 1024
#define BK    64
#define NSTEP (KPER / BK)        // 16
#define LDK   72                 // BK + 8 halves pad (144B row: 16B-aligned, 2-way banks)

// ---- workspace layout (bytes) ----
#define COUNTS_OFF 0
#define GBASE_OFF  512
#define SEL_OFF    1024
#define WGT_OFF    (SEL_OFF + NFLAT * 4)
#define BH_OFF     (WGT_OFF + NFLAT * 4)
#define BO_OFF     (BH_OFF + NEXP * NBLK * 4)
#define PART_OFF   (BO_OFF + NEXP * NBLK * 4)   // + KSPLIT*NT*NEXP*4 = 32 MB

// fp32 -> fp16 high + scaled-residual (m captures next 11 bits, kept normal-range)
__device__ __forceinline__ void split2(float v, f16& h, f16& m) {
    h = (f16)v;
    m = (f16)((v - (float)h) * 2048.0f);
}

// ============ GEMM: partial[s][tok][e] = x @ (64*gw)^T via 3-MFMA fp16 split ============
__global__ __launch_bounds__(256, 2)
void gemm_kernel(const float* __restrict__ x, const float* __restrict__ gw,
                 float* __restrict__ partial) {
    __shared__ f16 xh[128][LDK], xm[128][LDK], wh[128][LDK], wm[128][LDK];

    const int tid  = threadIdx.x;
    const int tok0 = blockIdx.x * 128;
    const int s    = blockIdx.y;
    const int lr   = tid >> 4;          // staging row-in-group
    const int lk   = (tid & 15) * 4;    // staging k offset

    const int lane = tid & 63, wid = tid >> 6;
    const int wr = wid >> 1, wc = wid & 1;
    const int fr = lane & 15, hi = lane >> 4;

    f32x4 acc0[4][4], acc1[4][4];
#pragma unroll
    for (int i = 0; i < 4; ++i)
#pragma unroll
        for (int j = 0; j < 4; ++j) {
            acc0[i][j] = (f32x4){0.f, 0.f, 0.f, 0.f};
            acc1[i][j] = (f32x4){0.f, 0.f, 0.f, 0.f};
        }

    for (int st = 0; st < NSTEP; ++st) {
        const int k0 = s * KPER + st * BK;
#pragma unroll
        for (int r = 0; r < 8; ++r) {
            int row = r * 16 + lr;
            float4 v = *(const float4*)&x[(size_t)(tok0 + row) * DIM + k0 + lk];
            f16 h0, m0, h1, m1, h2, m2, h3, m3;
            split2(v.x, h0, m0); split2(v.y, h1, m1);
            split2(v.z, h2, m2); split2(v.w, h3, m3);
            union { f16 f[4]; uint2 u; } ph = {{h0, h1, h2, h3}}, pm = {{m0, m1, m2, m3}};
            *(uint2*)&xh[row][lk] = ph.u;
            *(uint2*)&xm[row][lk] = pm.u;
        }
#pragma unroll
        for (int r = 0; r < 8; ++r) {
            int row = r * 16 + lr;
            float4 v = *(const float4*)&gw[(size_t)row * DIM + k0 + lk];
            f16 h0, m0, h1, m1, h2, m2, h3, m3;
            split2(v.x * 64.f, h0, m0); split2(v.y * 64.f, h1, m1);
            split2(v.z * 64.f, h2, m2); split2(v.w * 64.f, h3, m3);
            union { f16 f[4]; uint2 u; } ph = {{h0, h1, h2, h3}}, pm = {{m0, m1, m2, m3}};
            *(uint2*)&wh[row][lk] = ph.u;
            *(uint2*)&wm[row][lk] = pm.u;
        }
        __syncthreads();
#pragma unroll
        for (int kk = 0; kk < 2; ++kk) {
            f16x8 ah[4], am[4];
#pragma unroll
            for (int i = 0; i < 4; ++i) {
                ah[i] = *(const f16x8*)&xh[wr * 64 + i * 16 + fr][kk * 32 + hi * 8];
                am[i] = *(const f16x8*)&xm[wr * 64 + i * 16 + fr][kk * 32 + hi * 8];
            }
#pragma unroll
            for (int j = 0; j < 4; ++j) {
                f16x8 bhf = *(const f16x8*)&wh[wc * 64 + j * 16 + fr][kk * 32 + hi * 8];
                f16x8 bmf = *(const f16x8*)&wm[wc * 64 + j * 16 + fr][kk * 32 + hi * 8];
#pragma unroll
                for (int i = 0; i < 4; ++i) {
                    acc0[i][j] = __builtin_amdgcn_mfma_f32_16x16x32_f16(ah[i], bhf, acc0[i][j], 0, 0, 0);
                    acc1[i][j] = __builtin_amdgcn_mfma_f32_16x16x32_f16(ah[i], bmf, acc1[i][j], 0, 0, 0);
                    acc1[i][j] = __builtin_amdgcn_mfma_f32_16x16x32_f16(am[i], bhf, acc1[i][j], 0, 0, 0);
                }
            }
        }
        __syncthreads();
    }

    // epilogue: undo the w*64 scale and the m*2048 scale
#pragma unroll
    for (int i = 0; i < 4; ++i)
#pragma unroll
        for (int j = 0; j < 4; ++j)
#pragma unroll
            for (int q = 0; q < 4; ++q) {
                int tok = tok0 + wr * 64 + i * 16 + hi * 4 + q;
                int e   = wc * 64 + j * 16 + fr;
                float v = (acc0[i][j][q] + acc1[i][j][q] * (1.0f / 2048.0f)) * (1.0f / 64.0f);
                partial[((size_t)s * NT + tok) * NEXP + e] = v;
            }
}

// ============ wave-per-token top-8 + softmax-over-8 ============
__global__ __launch_bounds__(256)
void topk_kernel(const float* __restrict__ partial, float* __restrict__ wgt,
                 int* __restrict__ sel, int* __restrict__ counts) {
    const int lane = threadIdx.x & 63;
    const int t = blockIdx.x * 4 + (threadIdx.x >> 6);

    float s0 = 0.f, s1 = 0.f;
#pragma unroll
    for (int s = 0; s < KSPLIT; ++s) {
        s0 += partial[((size_t)s * NT + t) * NEXP + lane];
        s1 += partial[((size_t)s * NT + t) * NEXP + 64 + lane];
    }
    const int e0 = lane, e1 = 64 + lane;

    float bs[8]; int bi[8];
#pragma unroll
    for (int r = 0; r < 8; ++r) {
        bool p = (s0 >= s1);              // e0 < e1: prefer e0 on tie
        float v = p ? s0 : s1;
        int   e = p ? e0 : e1;
#pragma unroll
        for (int d = 1; d < 64; d <<= 1) {
            float ov = __shfl_xor(v, d);
            int   oe = __shfl_xor(e, d);
            if (ov > v || (ov == v && oe < e)) { v = ov; e = oe; }
        }
        bs[r] = v; bi[r] = e;
        if (e == e0) s0 = -3.0e38f;
        if (e == e1) s1 = -3.0e38f;
    }

    float m = bs[0], sum = 0.f, ex[8];
#pragma unroll
    for (int r = 0; r < 8; ++r) { ex[r] = expf(bs[r] - m); sum += ex[r]; }
    float inv = 1.f / fmaxf(sum, 1e-8f);

    float myw = 0.f; int mye = 0;
#pragma unroll
    for (int r = 0; r < 8; ++r)
        if (lane == r) { myw = ex[r] * inv; mye = bi[r]; }
    if (lane < 8) {
        wgt[t * TOPK + lane] = myw;
        sel[t * TOPK + lane] = mye;
        atomicAdd(&counts[mye], 1);
    }
}

// ============ stable sort: hist -> (base | block-scan) -> scatter ============
__global__ void hist_kernel(const int* __restrict__ sel, int* __restrict__ bh) {
    __shared__ int h[NEXP];
    const int tid = threadIdx.x, b = blockIdx.x;
    if (tid < NEXP) h[tid] = 0;
    __syncthreads();
    atomicAdd(&h[sel[b * 256 + tid]], 1);
    __syncthreads();
    if (tid < NEXP) bh[tid * NBLK + b] = h[tid];
}

__global__ void base_kernel(const int* __restrict__ counts, int* __restrict__ gbase,
                            float* __restrict__ out) {
    __shared__ int sc[NEXP];
    const int tid = threadIdx.x;   // 128
    int c = counts[tid];
    int v = c;
    sc[tid] = v;
    __syncthreads();
    for (int d = 1; d < NEXP; d <<= 1) {
        int o = (tid >= d) ? sc[tid - d] : 0;
        __syncthreads();
        v += o;
        sc[tid] = v;
        __syncthreads();
    }
    gbase[tid] = v - c;                 // exclusive prefix
    out[2 * NFLAT + tid] = (float)c;    // num_tokens_per_expert
}

__global__ void scan_kernel(const int* __restrict__ bh, int* __restrict__ bo) {
    const int e = blockIdx.x, tid = threadIdx.x;   // 512 threads
    const int lane = tid & 63, wid = tid >> 6;
    int v = bh[e * NBLK + tid];
    int sc = v;
#pragma unroll
    for (int d = 1; d < 64; d <<= 1) {
        int o = __shfl_up(sc, d);
        sc += (lane >= d) ? o : 0;
    }
    __shared__ int wsum[8];
    if (lane == 63) wsum[wid] = sc;
    __syncthreads();
    int add = 0;
#pragma unroll
    for (int w = 0; w < 8; w++) add += (w < wid) ? wsum[w] : 0;
    bo[e * NBLK + tid] = sc - v + add;
}

__global__ void scatter_kernel(const int* __restrict__ sel, const float* __restrict__ wgt,
                               const int* __restrict__ bo, const int* __restrict__ gbase,
                               float* __restrict__ out) {
    const int tid = threadIdx.x, b = blockIdx.x;
    const int i = b * 256 + tid;
    const int e = sel[i];
    const int lane = tid & 63, wid = tid >> 6;
    unsigned long long m = ~0ull;
#pragma unroll
    for (int bit = 0; bit < 7; bit++) {
        unsigned long long bal = __ballot((e >> bit) & 1);
        m &= ((e >> bit) & 1) ? bal : ~bal;
    }
    unsigned long long lower = (lane == 0) ? 0ull : (~0ull >> (64 - lane));
    int wrank = __popcll(m & lower);

    __shared__ int wh_[4][NEXP];
    ((int*)wh_)[tid] = 0; ((int*)wh_)[tid + 256] = 0;
    __syncthreads();
    if (wrank == 0) wh_[wid][e] = __popcll(m);
    __syncthreads();
    int off = 0;
#pragma unroll
    for (int w = 0; w < 4; w++) off += (w < wid) ? wh_[w][e] : 0;

    int pos = gbase[e] + bo[e * NBLK + b] + off + wrank;
    out[pos] = wgt[i];
    out[NFLAT + pos] = (float)(i >> 3);
}

extern "C" void kernel_launch(void* const* d_in, const int* in_sizes, int n_in,
                              void* d_out, int out_size, void* d_ws, size_t ws_size,
                              hipStream_t stream) {
    const float* x  = (const float*)d_in[0];
    const float* gw = (const float*)d_in[1];
    float* out = (float*)d_out;
    char*  ws  = (char*)d_ws;

    int*   counts  = (int*)(ws + COUNTS_OFF);
    int*   gbase   = (int*)(ws + GBASE_OFF);
    int*   sel     = (int*)(ws + SEL_OFF);
    float* wgt     = (float*)(ws + WGT_OFF);
    int*   bh      = (int*)(ws + BH_OFF);
    int*   bo      = (int*)(ws + BO_OFF);
    float* partial = (float*)(ws + PART_OFF);

    hipMemsetAsync(counts, 0, NEXP * sizeof(int), stream);

    gemm_kernel<<<dim3(NT / 128, KSPLIT), 256, 0, stream>>>(x, gw, partial);
    topk_kernel<<<NT / 4, 256, 0, stream>>>(partial, wgt, sel, counts);
    hist_kernel<<<NBLK, 256, 0, stream>>>(sel, bh);
    base_kernel<<<1, NEXP, 0, stream>>>(counts, gbase, out);
    scan_kernel<<<NEXP, 512, 0, stream>>>(bh, bo);
    scatter_kernel<<<NBLK, 256, 0, stream>>>(sel, wgt, bo, gbase, out);
}

// Round 4
// 230.791 us; speedup vs baseline: 2.3824x; 1.6542x over previous
//
#include <hip/hip_runtime.h>
#include <math.h>

typedef _Float16 f16;
typedef f16 f16x8 __attribute__((ext_vector_type(8)));
typedef float f32x4 __attribute__((ext_vector_type(4)));

#define NT    16384
#define DIM   4096
#define NEXP  128
#define TOPK  8
#define NFLAT (NT * TOPK)        // 131072
#define NBLK  (NFLAT / 256)      // 512
#define BK    64
#define NSTEP (DIM / BK)         // 64
#define LDK   72                 // 64 + 8 halves pad: 144B rows, 16B-aligned

// ---- workspace layout (bytes) ----
#define COUNTS_OFF 0
#define GBASE_OFF  512
#define SEL_OFF    1024
#define WGT_OFF    (SEL_OFF + NFLAT * 4)
#define BH_OFF     (WGT_OFF + NFLAT * 4)
#define BO_OFF     (BH_OFF + NEXP * NBLK * 4)

// ---- LDS layout (bytes): 2 buffers each of XH/XM[64][LDK], WH/WM[128][LDK]
#define XH_OFF 0
#define XM_OFF 18432
#define WH_OFF 36864
#define WM_OFF 73728
#define SMEM_SZ 110592
#define LDS_S 132   // epilogue score stride (floats)

// fp32 -> fp16 high + scaled residual (next ~11 mantissa bits, normal range)
__device__ __forceinline__ void split2(float v, f16& h, f16& m) {
    h = (f16)v;
    m = (f16)((v - (float)h) * 2048.0f);
}

// ============ fused: scores = x @ (64*gw)^T  -> top-8 -> softmax -> sel/wgt ============
__global__ __launch_bounds__(512, 1)
void fused_kernel(const float* __restrict__ x, const float* __restrict__ gw,
                  float* __restrict__ wgt, int* __restrict__ sel,
                  int* __restrict__ counts) {
    __shared__ __align__(16) char smem[SMEM_SZ];
    f16* XH = (f16*)(smem + XH_OFF);
    f16* XM = (f16*)(smem + XM_OFF);
    f16* WH = (f16*)(smem + WH_OFF);
    f16* WM = (f16*)(smem + WM_OFF);
    float* S = (float*)smem;     // epilogue reuse: 64*LDS_S*4 = 33792 B

    const int tid  = threadIdx.x;
    const int tok0 = blockIdx.x * 64;
    const int lane = tid & 63, wid = tid >> 6;
    const int tr = wid >> 2, ec = wid & 3;           // wave tile: 32 tok x 32 exp
    const int fr = lane & 15, hi = lane >> 4;
    const int srow = tid >> 4;                       // staging row 0..31
    const int skq  = (tid & 15) * 4;                 // staging k offset (floats)

    f32x4 acc0[2][2], acc1[2][2];
#pragma unroll
    for (int i = 0; i < 2; ++i)
#pragma unroll
        for (int j = 0; j < 2; ++j) {
            acc0[i][j] = (f32x4){0.f, 0.f, 0.f, 0.f};
            acc1[i][j] = (f32x4){0.f, 0.f, 0.f, 0.f};
        }

    float4 rx0, rx1, rw0, rw1, rw2, rw3;
    // prologue: load K-step 0
    rx0 = *(const float4*)&x[(size_t)(tok0 + srow) * DIM + skq];
    rx1 = *(const float4*)&x[(size_t)(tok0 + srow + 32) * DIM + skq];
    rw0 = *(const float4*)&gw[(size_t)(srow)      * DIM + skq];
    rw1 = *(const float4*)&gw[(size_t)(srow + 32) * DIM + skq];
    rw2 = *(const float4*)&gw[(size_t)(srow + 64) * DIM + skq];
    rw3 = *(const float4*)&gw[(size_t)(srow + 96) * DIM + skq];

    for (int st = 0; st < NSTEP; ++st) {
        const int cur = st & 1;
        // ---- split + write regs -> LDS[cur] ----
        {
            f16 h0,m0,h1,m1,h2,m2,h3,m3;
            union { f16 f[4]; uint2 u; } ph, pm;

            split2(rx0.x,h0,m0); split2(rx0.y,h1,m1); split2(rx0.z,h2,m2); split2(rx0.w,h3,m3);
            ph.f[0]=h0; ph.f[1]=h1; ph.f[2]=h2; ph.f[3]=h3;
            pm.f[0]=m0; pm.f[1]=m1; pm.f[2]=m2; pm.f[3]=m3;
            *(uint2*)&XH[(size_t)(cur*64 + srow) * LDK + skq] = ph.u;
            *(uint2*)&XM[(size_t)(cur*64 + srow) * LDK + skq] = pm.u;

            split2(rx1.x,h0,m0); split2(rx1.y,h1,m1); split2(rx1.z,h2,m2); split2(rx1.w,h3,m3);
            ph.f[0]=h0; ph.f[1]=h1; ph.f[2]=h2; ph.f[3]=h3;
            pm.f[0]=m0; pm.f[1]=m1; pm.f[2]=m2; pm.f[3]=m3;
            *(uint2*)&XH[(size_t)(cur*64 + srow + 32) * LDK + skq] = ph.u;
            *(uint2*)&XM[(size_t)(cur*64 + srow + 32) * LDK + skq] = pm.u;

            split2(rw0.x*64.f,h0,m0); split2(rw0.y*64.f,h1,m1); split2(rw0.z*64.f,h2,m2); split2(rw0.w*64.f,h3,m3);
            ph.f[0]=h0; ph.f[1]=h1; ph.f[2]=h2; ph.f[3]=h3;
            pm.f[0]=m0; pm.f[1]=m1; pm.f[2]=m2; pm.f[3]=m3;
            *(uint2*)&WH[(size_t)(cur*128 + srow) * LDK + skq] = ph.u;
            *(uint2*)&WM[(size_t)(cur*128 + srow) * LDK + skq] = pm.u;

            split2(rw1.x*64.f,h0,m0); split2(rw1.y*64.f,h1,m1); split2(rw1.z*64.f,h2,m2); split2(rw1.w*64.f,h3,m3);
            ph.f[0]=h0; ph.f[1]=h1; ph.f[2]=h2; ph.f[3]=h3;
            pm.f[0]=m0; pm.f[1]=m1; pm.f[2]=m2; pm.f[3]=m3;
            *(uint2*)&WH[(size_t)(cur*128 + srow + 32) * LDK + skq] = ph.u;
            *(uint2*)&WM[(size_t)(cur*128 + srow + 32) * LDK + skq] = pm.u;

            split2(rw2.x*64.f,h0,m0); split2(rw2.y*64.f,h1,m1); split2(rw2.z*64.f,h2,m2); split2(rw2.w*64.f,h3,m3);
            ph.f[0]=h0; ph.f[1]=h1; ph.f[2]=h2; ph.f[3]=h3;
            pm.f[0]=m0; pm.f[1]=m1; pm.f[2]=m2; pm.f[3]=m3;
            *(uint2*)&WH[(size_t)(cur*128 + srow + 64) * LDK + skq] = ph.u;
            *(uint2*)&WM[(size_t)(cur*128 + srow + 64) * LDK + skq] = pm.u;

            split2(rw3.x*64.f,h0,m0); split2(rw3.y*64.f,h1,m1); split2(rw3.z*64.f,h2,m2); split2(rw3.w*64.f,h3,m3);
            ph.f[0]=h0; ph.f[1]=h1; ph.f[2]=h2; ph.f[3]=h3;
            pm.f[0]=m0; pm.f[1]=m1; pm.f[2]=m2; pm.f[3]=m3;
            *(uint2*)&WH[(size_t)(cur*128 + srow + 96) * LDK + skq] = ph.u;
            *(uint2*)&WM[(size_t)(cur*128 + srow + 96) * LDK + skq] = pm.u;
        }
        // ---- issue next-step loads early (overlap with barrier + MFMA) ----
        if (st + 1 < NSTEP) {
            const size_t k0 = (size_t)(st + 1) * BK + skq;
            rx0 = *(const float4*)&x[(size_t)(tok0 + srow) * DIM + k0];
            rx1 = *(const float4*)&x[(size_t)(tok0 + srow + 32) * DIM + k0];
            rw0 = *(const float4*)&gw[(size_t)(srow)      * DIM + k0];
            rw1 = *(const float4*)&gw[(size_t)(srow + 32) * DIM + k0];
            rw2 = *(const float4*)&gw[(size_t)(srow + 64) * DIM + k0];
            rw3 = *(const float4*)&gw[(size_t)(srow + 96) * DIM + k0];
        }
        __syncthreads();
        // ---- compute buf[cur]: 24 MFMA ----
#pragma unroll
        for (int kk = 0; kk < 2; ++kk) {
            f16x8 ah[2], am[2];
#pragma unroll
            for (int i = 0; i < 2; ++i) {
                int r = cur * 64 + tr * 32 + i * 16 + fr;
                ah[i] = *(const f16x8*)&XH[(size_t)r * LDK + kk * 32 + hi * 8];
                am[i] = *(const f16x8*)&XM[(size_t)r * LDK + kk * 32 + hi * 8];
            }
#pragma unroll
            for (int j = 0; j < 2; ++j) {
                int r = cur * 128 + ec * 32 + j * 16 + fr;
                f16x8 bh = *(const f16x8*)&WH[(size_t)r * LDK + kk * 32 + hi * 8];
                f16x8 bm = *(const f16x8*)&WM[(size_t)r * LDK + kk * 32 + hi * 8];
#pragma unroll
                for (int i = 0; i < 2; ++i) {
                    acc0[i][j] = __builtin_amdgcn_mfma_f32_16x16x32_f16(ah[i], bh, acc0[i][j], 0, 0, 0);
                    acc1[i][j] = __builtin_amdgcn_mfma_f32_16x16x32_f16(ah[i], bm, acc1[i][j], 0, 0, 0);
                    acc1[i][j] = __builtin_amdgcn_mfma_f32_16x16x32_f16(am[i], bh, acc1[i][j], 0, 0, 0);
                }
            }
        }
        __syncthreads();
    }

    // ---- scores -> LDS (undo w*64 and m*2048 scales) ----
#pragma unroll
    for (int i = 0; i < 2; ++i)
#pragma unroll
        for (int j = 0; j < 2; ++j)
#pragma unroll
            for (int q = 0; q < 4; ++q) {
                int t = tr * 32 + i * 16 + hi * 4 + q;
                int e = ec * 32 + j * 16 + fr;
                float v = (acc0[i][j][q] + acc1[i][j][q] * (1.0f / 2048.0f)) * (1.0f / 64.0f);
                S[t * LDS_S + e] = v;
            }
    __syncthreads();

    // ---- top-8 + softmax-over-8: 64 threads, one token each ----
    if (tid < 64) {
        float bs[8]; int bi[8];
#pragma unroll
        for (int r = 0; r < 8; ++r) { bs[r] = -3.0e38f; bi[r] = 0; }
        for (int e = 0; e < NEXP; ++e) {
            float s = S[tid * LDS_S + e];
            if (s > bs[7]) {
                int pos = 7;
#pragma unroll
                for (int q = 6; q >= 0; q--) pos = (s > bs[q]) ? q : pos;
#pragma unroll
                for (int q = 7; q >= 1; q--) {
                    bool sh = (q > pos);
                    bs[q] = sh ? bs[q - 1] : bs[q];
                    bi[q] = sh ? bi[q - 1] : bi[q];
                }
#pragma unroll
                for (int q = 0; q < 8; q++)
                    if (q == pos) { bs[q] = s; bi[q] = e; }
            }
        }
        float m = bs[0], sum = 0.f, ex[8];
#pragma unroll
        for (int r = 0; r < 8; ++r) { ex[r] = expf(bs[r] - m); sum += ex[r]; }
        float inv = 1.f / fmaxf(sum, 1e-8f);
        const int tok = tok0 + tid;
#pragma unroll
        for (int r = 0; r < 8; ++r) {
            wgt[tok * TOPK + r] = ex[r] * inv;
            sel[tok * TOPK + r] = bi[r];
            atomicAdd(&counts[bi[r]], 1);
        }
    }
}

// ============ stable sort: hist -> (base | block-scan) -> scatter ============
__global__ void hist_kernel(const int* __restrict__ sel, int* __restrict__ bh) {
    __shared__ int h[NEXP];
    const int tid = threadIdx.x, b = blockIdx.x;
    if (tid < NEXP) h[tid] = 0;
    __syncthreads();
    atomicAdd(&h[sel[b * 256 + tid]], 1);
    __syncthreads();
    if (tid < NEXP) bh[tid * NBLK + b] = h[tid];
}

__global__ void base_kernel(const int* __restrict__ counts, int* __restrict__ gbase,
                            float* __restrict__ out) {
    __shared__ int sc[NEXP];
    const int tid = threadIdx.x;   // 128
    int c = counts[tid];
    int v = c;
    sc[tid] = v;
    __syncthreads();
    for (int d = 1; d < NEXP; d <<= 1) {
        int o = (tid >= d) ? sc[tid - d] : 0;
        __syncthreads();
        v += o;
        sc[tid] = v;
        __syncthreads();
    }
    gbase[tid] = v - c;
    out[2 * NFLAT + tid] = (float)c;
}

__global__ void scan_kernel(const int* __restrict__ bh, int* __restrict__ bo) {
    const int e = blockIdx.x, tid = threadIdx.x;   // 512 threads
    const int lane = tid & 63, wid = tid >> 6;
    int v = bh[e * NBLK + tid];
    int sc = v;
#pragma unroll
    for (int d = 1; d < 64; d <<= 1) {
        int o = __shfl_up(sc, d);
        sc += (lane >= d) ? o : 0;
    }
    __shared__ int wsum[8];
    if (lane == 63) wsum[wid] = sc;
    __syncthreads();
    int add = 0;
#pragma unroll
    for (int w = 0; w < 8; w++) add += (w < wid) ? wsum[w] : 0;
    bo[e * NBLK + tid] = sc - v + add;
}

__global__ void scatter_kernel(const int* __restrict__ sel, const float* __restrict__ wgt,
                               const int* __restrict__ bo, const int* __restrict__ gbase,
                               float* __restrict__ out) {
    const int tid = threadIdx.x, b = blockIdx.x;
    const int i = b * 256 + tid;
    const int e = sel[i];
    const int lane = tid & 63, wid = tid >> 6;
    unsigned long long m = ~0ull;
#pragma unroll
    for (int bit = 0; bit < 7; bit++) {
        unsigned long long bal = __ballot((e >> bit) & 1);
        m &= ((e >> bit) & 1) ? bal : ~bal;
    }
    unsigned long long lower = (lane == 0) ? 0ull : (~0ull >> (64 - lane));
    int wrank = __popcll(m & lower);

    __shared__ int wh_[4][NEXP];
    ((int*)wh_)[tid] = 0; ((int*)wh_)[tid + 256] = 0;
    __syncthreads();
    if (wrank == 0) wh_[wid][e] = __popcll(m);
    __syncthreads();
    int off = 0;
#pragma unroll
    for (int w = 0; w < 4; w++) off += (w < wid) ? wh_[w][e] : 0;

    int pos = gbase[e] + bo[e * NBLK + b] + off + wrank;
    out[pos] = wgt[i];
    out[NFLAT + pos] = (float)(i >> 3);
}

extern "C" void kernel_launch(void* const* d_in, const int* in_sizes, int n_in,
                              void* d_out, int out_size, void* d_ws, size_t ws_size,
                              hipStream_t stream) {
    const float* x  = (const float*)d_in[0];
    const float* gw = (const float*)d_in[1];
    float* out = (float*)d_out;
    char*  ws  = (char*)d_ws;

    int*   counts = (int*)(ws + COUNTS_OFF);
    int*   gbase  = (int*)(ws + GBASE_OFF);
    int*   sel    = (int*)(ws + SEL_OFF);
    float* wgt    = (float*)(ws + WGT_OFF);
    int*   bh     = (int*)(ws + BH_OFF);
    int*   bo     = (int*)(ws + BO_OFF);

    hipMemsetAsync(counts, 0, NEXP * sizeof(int), stream);

    fused_kernel<<<NT / 64, 512, 0, stream>>>(x, gw, wgt, sel, counts);
    hist_kernel<<<NBLK, 256, 0, stream>>>(sel, bh);
    base_kernel<<<1, NEXP, 0, stream>>>(counts, gbase, out);
    scan_kernel<<<NEXP, 512, 0, stream>>>(bh, bo);
    scatter_kernel<<<NBLK, 256, 0, stream>>>(sel, wgt, bo, gbase, out);
}